// Round 15
// baseline (229.970 us; speedup 1.0000x reference)
//
#include <hip/hip_runtime.h>
#include <math.h>
#include <stdint.h>
#include <stddef.h>

// CRITICAL: the reference check is vs a dtype-faithful f32 pipeline.
// FMA contraction in the delta/enc path perturbs floor(enc*scale) cells
// (each flip = ~1e-4 error >> 2e-6 threshold). Force separate rounding.
#pragma clang fp contract(off)

// feats: (3, 64, 100, 256) f32; table: (TOTAL_ENTRIES, 2) f32
// transposed feat layout in ws: [i][ (j*100+t)*256 + x ][c], c contiguous
#define TFEAT_ELEMS 4915200  // 3*100*256*64 per feat tensor

struct HashMeta {
  float     scalef[16];
  long long offs[16];
  long long s1[16];
  long long nent;
  unsigned long long magic;
  int start_hash;
};

__device__ __forceinline__ long long mod_ne(long long v, long long nent,
                                            unsigned long long magic) {
  unsigned long long uv = (unsigned long long)v;
  unsigned long long q  = __umul64hi(uv, magic);
  unsigned long long r  = uv - q * (unsigned long long)nent;
  if (r >= (unsigned long long)nent) r -= (unsigned long long)nent;
  return (long long)r;
}

__device__ __forceinline__ float rlane(float v, int l) {
  return __int_as_float(__builtin_amdgcn_readlane(__float_as_int(v), l));
}

// ---------------- feat transpose: [j][c][t][x] -> [(j*100+t)*256+x][c] ----
// Block = (i, jt, x-half): reads 1KB contiguous per c-row (good HBM row
// locality), writes 64-float contiguous per x-row. LDS [64][129] = 33KB.
__global__ __launch_bounds__(256)
void transpose_feats_k(const float* __restrict__ F0, const float* __restrict__ F1,
                       const float* __restrict__ F2, float* __restrict__ T)
{
  __shared__ float tile[64][129];
  const int i  = blockIdx.y;
  const float* F = (i == 0) ? F0 : ((i == 1) ? F1 : F2);
  const int b  = blockIdx.x;        // 0..599
  const int jt = b >> 1;            // 0..299
  const int xb = (b & 1) << 7;      // 0 or 128
  const int j  = jt / 100;
  const int t  = jt - j * 100;
  const int tid = threadIdx.x;
  {
    const int c = tid >> 2;         // 0..63
    const int q = tid & 3;          // 0..3
    const float* src = F + ((size_t)(j*64 + c)*100 + t)*256 + xb;
    #pragma unroll
    for (int p = 0; p < 8; ++p) {
      const int x4 = (q*8 + p) * 4; // 0..124
      const float4 v = *reinterpret_cast<const float4*>(src + x4);
      tile[c][x4+0] = v.x;
      tile[c][x4+1] = v.y;
      tile[c][x4+2] = v.z;
      tile[c][x4+3] = v.w;
    }
  }
  __syncthreads();
  {
    float* dst = T + (size_t)i * TFEAT_ELEMS + (size_t)jt * 256 * 64;
    const int xl = tid >> 1;        // 0..127
    const int h  = tid & 1;         // 0..1
    #pragma unroll
    for (int p = 0; p < 8; ++p) {
      const int c4 = (h*8 + p) * 4; // 0..60
      float4 v;
      v.x = tile[c4+0][xl];
      v.y = tile[c4+1][xl];
      v.z = tile[c4+2][xl];
      v.w = tile[c4+3][xl];
      *reinterpret_cast<float4*>(dst + (size_t)(xb + xl)*64 + c4) = v;
    }
  }
}

// ------- t-bucket sort, atomic-free (parallel scan; order-independent) ----
__device__ __forceinline__ int clamp_t(float tf) {
  int t = (int)tf;
  return t < 0 ? 0 : (t > 99 ? 99 : t);
}

// pass 1: per-block LDS histogram -> Hb[b][100]
__global__ __launch_bounds__(256)
void sort_hist_k(const float* __restrict__ xin, int* __restrict__ Hb, int npts)
{
  __shared__ int h[100];
  if (threadIdx.x < 100) h[threadIdx.x] = 0;
  __syncthreads();
  const int n = blockIdx.x * 256 + threadIdx.x;
  if (n < npts) atomicAdd(&h[clamp_t(xin[(size_t)n*4 + 3])], 1);
  __syncthreads();
  if (threadIdx.x < 100) Hb[blockIdx.x * 100 + threadIdx.x] = h[threadIdx.x];
}

// pass 2: per-bucket parallel exclusive prefix over blocks (chunked H-S)
// grid = 100 blocks (one per t), 256 threads
__global__ __launch_bounds__(256)
void sort_scan1_k(const int* __restrict__ Hb, int* __restrict__ Ob,
                  int* __restrict__ tot, int nb)
{
  __shared__ int s[256];
  const int t = blockIdx.x;
  int carry = 0;
  for (int base = 0; base < nb; base += 256) {
    const int b = base + (int)threadIdx.x;
    const int v = (b < nb) ? Hb[b*100 + t] : 0;
    s[threadIdx.x] = v;
    __syncthreads();
    #pragma unroll
    for (int o = 1; o < 256; o <<= 1) {
      const int add = (threadIdx.x >= (unsigned)o) ? s[threadIdx.x - o] : 0;
      __syncthreads();
      s[threadIdx.x] += add;
      __syncthreads();
    }
    const int incl = s[threadIdx.x];
    if (b < nb) Ob[b*100 + t] = carry + (incl - v);
    carry += s[255];
    __syncthreads();
  }
  if (threadIdx.x == 0) tot[t] = carry;
}

// pass 3: per-block goff scan (LDS) + LDS rank + scatter (no global atomics)
__global__ __launch_bounds__(256)
void sort_scatter_k(const float* __restrict__ xin, const int* __restrict__ Ob,
                    const int* __restrict__ tot, int* __restrict__ idx, int npts)
{
  __shared__ int goff[100];
  __shared__ int cnt[100];
  if (threadIdx.x < 100) {
    goff[threadIdx.x] = tot[threadIdx.x];
    cnt[threadIdx.x]  = 0;
  }
  __syncthreads();
  if (threadIdx.x == 0) {
    int acc = 0;
    for (int u = 0; u < 100; ++u) { const int v = goff[u]; goff[u] = acc; acc += v; }
  }
  __syncthreads();
  const int n = blockIdx.x * 256 + threadIdx.x;
  if (n < npts) {
    const int t = clamp_t(xin[(size_t)n*4 + 3]);
    const int r = atomicAdd(&cnt[t], 1);   // LDS atomic: cheap
    idx[goff[t] + Ob[blockIdx.x * 100 + t] + r] = n;
  }
}

// ============ shared device helpers (exact reference op order) ============
struct Coords {
  float inp[3];
  int   yi0, yi1;
  float wy;
  bool  vy0, vy1;
  int   xi0[3], xi1[3];
  float wxv[3];
  bool  vx0[3], vx1[3];
};

__device__ __forceinline__ void compute_coords(const float px, const float py,
    const float pz, const float tfrm, const float* __restrict__ wbv, Coords& C)
{
  const float lo0 = wbv[0], lo1 = wbv[1], lo2 = wbv[2];
  const float hi0 = wbv[3], hi1 = wbv[4], hi2 = wbv[5];
  const float den = fmaxf(fmaxf(hi0-lo0, hi1-lo1), hi2-lo2);
  C.inp[0] = (fminf(fmaxf(px, lo0), hi0) - lo0) / den;
  C.inp[1] = (fminf(fmaxf(py, lo1), hi1) - lo1) / den;
  C.inp[2] = (fminf(fmaxf(pz, lo2), hi2) - lo2) / den;
  const float tn = tfrm / 99.0f;
  const float gy  = ((2.0f*tn - 1.0f) + 1.0f) * 0.5f * 99.0f;
  const float y0f = floorf(gy);
  C.wy  = gy - y0f;
  const float y1f = y0f + 1.0f;
  C.vy0 = (y0f >= 0.0f) && (y0f <= 99.0f);
  C.vy1 = (y1f >= 0.0f) && (y1f <= 99.0f);
  C.yi0 = (int)fminf(fmaxf(y0f, 0.0f), 99.0f);
  C.yi1 = (int)fminf(fmaxf(y1f, 0.0f), 99.0f);
  #pragma unroll
  for (int j = 0; j < 3; ++j) {
    const float gx  = ((2.0f*C.inp[j] - 1.0f) + 1.0f) * 0.5f * 255.0f;
    const float x0f = floorf(gx);
    C.wxv[j] = gx - x0f;
    const float x1f = x0f + 1.0f;
    C.vx0[j] = (x0f >= 0.0f) && (x0f <= 255.0f);
    C.vx1[j] = (x1f >= 0.0f) && (x1f <= 255.0f);
    C.xi0[j] = (int)fminf(fmaxf(x0f, 0.0f), 255.0f);
    C.xi1[j] = (int)fminf(fmaxf(x1f, 0.0f), 255.0f);
  }
}

// prod over 3 planes (fallback path) — exact reference ops
template<bool TR>
__device__ __forceinline__ float plane_prod(const float* __restrict__ Fi,
    const Coords& C, const int c)
{
  float prod = 1.0f;
  #pragma unroll
  for (int j = 0; j < 3; ++j) {
    float v00, v10, v01, v11;
    if (TR) {
      const float* bp = Fi + (size_t)j*100*256*64 + c;
      v00 = bp[((size_t)C.yi0*256 + C.xi0[j])*64];
      v10 = bp[((size_t)C.yi0*256 + C.xi1[j])*64];
      v01 = bp[((size_t)C.yi1*256 + C.xi0[j])*64];
      v11 = bp[((size_t)C.yi1*256 + C.xi1[j])*64];
    } else {
      const float* bp = Fi + ((size_t)(j*64 + c)*100)*256;
      v00 = bp[(size_t)C.yi0*256 + C.xi0[j]];
      v10 = bp[(size_t)C.yi0*256 + C.xi1[j]];
      v01 = bp[(size_t)C.yi1*256 + C.xi0[j]];
      v11 = bp[(size_t)C.yi1*256 + C.xi1[j]];
    }
    v00 = (C.vx0[j] && C.vy0) ? v00 : 0.0f;
    v10 = (C.vx1[j] && C.vy0) ? v10 : 0.0f;
    v01 = (C.vx0[j] && C.vy1) ? v01 : 0.0f;
    v11 = (C.vx1[j] && C.vy1) ? v11 : 0.0f;
    const float s = v00 * ((1.0f - C.wxv[j]) * (1.0f - C.wy))
                  + v10 * (C.wxv[j] * (1.0f - C.wy))
                  + v01 * ((1.0f - C.wxv[j]) * C.wy)
                  + v11 * (C.wxv[j] * C.wy);
    prod *= s;
  }
  return prod;
}

// ====== K1 core: plane products for point n -> P[n][i][c] (bit-exact) =====
__device__ __forceinline__ void delta_point(const float4 xv,
    const float* __restrict__ wbv, const float* __restrict__ F0,
    const float* __restrict__ F1, const float* __restrict__ F2,
    float* __restrict__ P, int n, int lane)
{
  Coords C;
  compute_coords(xv.x, xv.y, xv.z, xv.w, wbv, C);

  const float* Fs[3] = {F0, F1, F2};
  // y1-row weights are exactly +/-0 when wy==0, and forced 0 when !vy1 —
  // skipping those loads is bit-exact.
  const bool skipY1 = (C.wy == 0.0f) || !C.vy1;

  float v[3][3][4];
  #pragma unroll
  for (int i = 0; i < 3; ++i) {
    #pragma unroll
    for (int j = 0; j < 3; ++j) {
      const float* bp = Fs[i] + (size_t)j*100*256*64 + lane;
      v[i][j][0] = bp[((size_t)C.yi0*256 + C.xi0[j])*64];
      v[i][j][1] = bp[((size_t)C.yi0*256 + C.xi1[j])*64];
    }
  }
  if (!skipY1) {
    #pragma unroll
    for (int i = 0; i < 3; ++i) {
      #pragma unroll
      for (int j = 0; j < 3; ++j) {
        const float* bp = Fs[i] + (size_t)j*100*256*64 + lane;
        v[i][j][2] = bp[((size_t)C.yi1*256 + C.xi0[j])*64];
        v[i][j][3] = bp[((size_t)C.yi1*256 + C.xi1[j])*64];
      }
    }
  } else {
    #pragma unroll
    for (int i = 0; i < 3; ++i)
      #pragma unroll
      for (int j = 0; j < 3; ++j) { v[i][j][2] = 0.0f; v[i][j][3] = 0.0f; }
  }

  float* Pn = P + (size_t)n * 192;
  #pragma unroll
  for (int i = 0; i < 3; ++i) {
    float prod = 1.0f;
    #pragma unroll
    for (int j = 0; j < 3; ++j) {
      const float v00 = (C.vx0[j] && C.vy0) ? v[i][j][0] : 0.0f;
      const float v10 = (C.vx1[j] && C.vy0) ? v[i][j][1] : 0.0f;
      const float v01 = (C.vx0[j] && C.vy1) ? v[i][j][2] : 0.0f;
      const float v11 = (C.vx1[j] && C.vy1) ? v[i][j][3] : 0.0f;
      const float s = v00 * ((1.0f - C.wxv[j]) * (1.0f - C.wy))
                    + v10 * (C.wxv[j] * (1.0f - C.wy))
                    + v01 * ((1.0f - C.wxv[j]) * C.wy)
                    + v11 * (C.wxv[j] * C.wy);
      prod *= s;
    }
    Pn[i*64 + lane] = prod;
  }
}

// ===== K1 (sorted): t-bucketed points, XCD-contiguous t-ranges =====
__global__ __launch_bounds__(256)
void delta_sorted_k(const float* __restrict__ xin, const float* __restrict__ wbv,
                    const float* __restrict__ F0, const float* __restrict__ F1,
                    const float* __restrict__ F2, const int* __restrict__ idx,
                    float* __restrict__ P, int npts)
{
  #pragma clang fp contract(off)
  const int lane = threadIdx.x & 63;
  const int nb   = gridDim.x;
  const int bid  = blockIdx.x;
  // XCD = dispatch id % 8 (heuristic). Give XCD k the contiguous sorted
  // range so its L2 streams ~12 t-values' feat rows once.
  const int sb   = ((nb & 7) == 0) ? ((bid & 7)*(nb >> 3) + (bid >> 3)) : bid;
  const int pos  = sb * 4 + (threadIdx.x >> 6);
  if (pos >= npts) return;
  const int n = idx[pos];

  const float4 xv = *reinterpret_cast<const float4*>(xin + (size_t)n*4);
  delta_point(xv, wbv, F0, F1, F2, P, n, lane);
}

// ===== K1 (unsorted fallback, round-11 passing) =====
__global__ __launch_bounds__(256)
void delta_prods_k(const float* __restrict__ xin, const float* __restrict__ wbv,
                   const float* __restrict__ F0, const float* __restrict__ F1,
                   const float* __restrict__ F2,
                   float* __restrict__ P, int npts)
{
  #pragma clang fp contract(off)
  const int lane = threadIdx.x & 63;
  const int nb   = gridDim.x;
  const int bid  = blockIdx.x;
  const int sb   = ((nb & 7) == 0) ? ((bid & 7)*(nb >> 3) + (bid >> 3)) : bid;
  const int n    = sb * 4 + (threadIdx.x >> 6);
  if (n >= npts) return;

  const float4 xv = *reinterpret_cast<const float4*>(xin + (size_t)n*4);
  delta_point(xv, wbv, F0, F1, F2, P, n, lane);
}

// ===== K2a: fold (exact c=0..63 order) + enc -> E[n] (float4) =====
__global__ __launch_bounds__(256)
void fold_enc_k(const float* __restrict__ xin, const float* __restrict__ wbv,
                const float* __restrict__ P, float4* __restrict__ E, int npts)
{
  #pragma clang fp contract(off)
  const int n = blockIdx.x * 256 + threadIdx.x;
  if (n >= npts) return;

  const float4 xv = *reinterpret_cast<const float4*>(xin + (size_t)n*4);
  const float lo0 = wbv[0], lo1 = wbv[1], lo2 = wbv[2];
  const float hi0 = wbv[3], hi1 = wbv[4], hi2 = wbv[5];
  const float den = fmaxf(fmaxf(hi0-lo0, hi1-lo1), hi2-lo2);
  float inp[3];
  inp[0] = (fminf(fmaxf(xv.x, lo0), hi0) - lo0) / den;
  inp[1] = (fminf(fmaxf(xv.y, lo1), hi1) - lo1) / den;
  inp[2] = (fminf(fmaxf(xv.z, lo2), hi2) - lo2) / den;

  const float* Pn = P + (size_t)n * 192;
  float delta[3];
  #pragma unroll
  for (int i = 0; i < 3; ++i) {
    const float4* Pi = reinterpret_cast<const float4*>(Pn + i*64);
    float4 q[16];
    #pragma unroll
    for (int k = 0; k < 16; ++k) q[k] = Pi[k];
    float acc = q[0].x;
    acc += q[0].y; acc += q[0].z; acc += q[0].w;
    #pragma unroll
    for (int k = 1; k < 16; ++k) {
      acc += q[k].x; acc += q[k].y; acc += q[k].z; acc += q[k].w;
    }
    delta[i] = acc;
  }

  const float emax = (float)(1.0 - 1e-6);
  float4 e;
  e.x = fminf(fmaxf(inp[0] + delta[0], 0.0f), emax);
  e.y = fminf(fmaxf(inp[1] + delta[1], 0.0f), emax);
  e.z = fminf(fmaxf(inp[2] + delta[2], 0.0f), emax);
  e.w = 0.0f;
  E[n] = e;
}

// ===== K2b: hash encode, ONE XCD PER LEVEL, coalesced Hout writes =====
__global__ __launch_bounds__(256)
void hash_swz_k(const float4* __restrict__ E, const float* __restrict__ table,
                float2* __restrict__ Hout, HashMeta m, int npts, int bx)
{
  #pragma clang fp contract(off)
  const int id   = blockIdx.x;
  const int xcd  = id & 7;
  const int slot = id >> 3;
  const int lh   = slot / bx;         // 0 or 1
  const int c    = slot - lh * bx;
  const int l    = xcd + 8 * lh;      // wave-uniform level
  const int n    = c * 256 + threadIdx.x;
  if (n >= npts) return;

  const float4 e = E[n];
  const float enc[3] = {e.x, e.y, e.z};

  const float sc = m.scalef[l];
  float i0f[3], i1f[3], off[3];
  long long j0[3], j1[3];
  #pragma unroll
  for (int d = 0; d < 3; ++d) {
    const float fx = enc[d] * sc;
    i0f[d] = floorf(fx);
    off[d] = fx - i0f[d];
    i1f[d] = floorf(fx + 1.0f);   // matches ref: floor(fx + corner)
    j0[d] = (long long)i0f[d];
    j1[d] = (long long)i1f[d];
  }
  const long long base = m.offs[l];
  const long long s1   = m.s1[l];
  const bool use_hash  = (l >= m.start_hash);
  long long ym0, ym1, zm0, zm1, xm0, xm1;
  if (use_hash) {
    ym0 = j0[1] * 19349663LL;  ym1 = j1[1] * 19349663LL;
    zm0 = j0[2] * 83492791LL;  zm1 = j1[2] * 83492791LL;
    xm0 = j0[0];               xm1 = j1[0];
  } else {
    const long long s1s = s1 * s1;
    xm0 = j0[0] * s1s;  xm1 = j1[0] * s1s;
    ym0 = j0[1] * s1;   ym1 = j1[1] * s1;
    zm0 = j0[2];        zm1 = j1[2];
  }
  float2 tv[8];
  float  wv[8];
  #pragma unroll
  for (int cc = 0; cc < 8; ++cc) {
    const int bxc = cc >> 2, byc = (cc >> 1) & 1, bzc = cc & 1;
    const long long xm = bxc ? xm1 : xm0;
    const long long ym = byc ? ym1 : ym0;
    const long long zm = bzc ? zm1 : zm0;
    long long idx;
    if (use_hash) {
      idx = mod_ne(xm ^ ym ^ zm, m.nent, m.magic) + base;
    } else {
      idx = xm + ym + zm + base;
    }
    tv[cc] = *reinterpret_cast<const float2*>(table + idx*2);
    wv[cc] = (bxc ? off[0] : 1.0f - off[0])
           * (byc ? off[1] : 1.0f - off[1])
           * (bzc ? off[2] : 1.0f - off[2]);
  }
  float a0 = 0.0f, a1 = 0.0f;
  #pragma unroll
  for (int cc = 0; cc < 8; ++cc) {
    a0 += wv[cc] * tv[cc].x;
    a1 += wv[cc] * tv[cc].y;
  }
  Hout[(size_t)l * npts + n] = make_float2(a0, a1);
}

// ===== K2c: Hout[l][n] -> out[n][l*2..] (both sides coalesced) =====
__global__ __launch_bounds__(256)
void untr_k(const float2* __restrict__ Hout, float* __restrict__ out, int npts)
{
  const int n = blockIdx.x * 256 + threadIdx.x;
  if (n >= npts) return;
  float2 v[16];
  #pragma unroll
  for (int l = 0; l < 16; ++l) v[l] = Hout[(size_t)l * npts + n];
  #pragma unroll
  for (int l = 0; l < 16; ++l)
    *reinterpret_cast<float2*>(out + (size_t)n*32 + l*2) = v[l];
}

// ===== fallback K2b (round-10 passing): level-major 2D, direct out =====
__global__ __launch_bounds__(256)
void hash_lvl_k(const float4* __restrict__ E, const float* __restrict__ table,
                float* __restrict__ out, HashMeta m, int npts)
{
  #pragma clang fp contract(off)
  const int l = blockIdx.y;
  const int n = blockIdx.x * 256 + threadIdx.x;
  if (n >= npts) return;

  const float4 e = E[n];
  const float enc[3] = {e.x, e.y, e.z};

  const float sc = m.scalef[l];
  float i0f[3], i1f[3], off[3];
  long long j0[3], j1[3];
  #pragma unroll
  for (int d = 0; d < 3; ++d) {
    const float fx = enc[d] * sc;
    i0f[d] = floorf(fx);
    off[d] = fx - i0f[d];
    i1f[d] = floorf(fx + 1.0f);
    j0[d] = (long long)i0f[d];
    j1[d] = (long long)i1f[d];
  }
  const long long base = m.offs[l];
  const long long s1   = m.s1[l];
  const bool use_hash  = (l >= m.start_hash);
  long long ym0, ym1, zm0, zm1, xm0, xm1;
  if (use_hash) {
    ym0 = j0[1] * 19349663LL;  ym1 = j1[1] * 19349663LL;
    zm0 = j0[2] * 83492791LL;  zm1 = j1[2] * 83492791LL;
    xm0 = j0[0];               xm1 = j1[0];
  } else {
    const long long s1s = s1 * s1;
    xm0 = j0[0] * s1s;  xm1 = j1[0] * s1s;
    ym0 = j0[1] * s1;   ym1 = j1[1] * s1;
    zm0 = j0[2];        zm1 = j1[2];
  }
  float2 tv[8];
  float  wv[8];
  #pragma unroll
  for (int cc = 0; cc < 8; ++cc) {
    const int bx = cc >> 2, by = (cc >> 1) & 1, bz = cc & 1;
    const long long xm = bx ? xm1 : xm0;
    const long long ym = by ? ym1 : ym0;
    const long long zm = bz ? zm1 : zm0;
    long long idx;
    if (use_hash) {
      idx = mod_ne(xm ^ ym ^ zm, m.nent, m.magic) + base;
    } else {
      idx = xm + ym + zm + base;
    }
    tv[cc] = *reinterpret_cast<const float2*>(table + idx*2);
    wv[cc] = (bx ? off[0] : 1.0f - off[0])
           * (by ? off[1] : 1.0f - off[1])
           * (bz ? off[2] : 1.0f - off[2]);
  }
  float a0 = 0.0f, a1 = 0.0f;
  #pragma unroll
  for (int cc = 0; cc < 8; ++cc) {
    a0 += wv[cc] * tv[cc].x;
    a1 += wv[cc] * tv[cc].y;
  }
  *reinterpret_cast<float2*>(out + (size_t)n*32 + l*2) = make_float2(a0, a1);
}

// ========== fallback: monolithic (readlane fold) ==========================
template<bool TR>
__global__ __launch_bounds__(256)
void dnerf_fused(const float* __restrict__ xin, const float* __restrict__ wbv,
                 const float* __restrict__ table,
                 const float* __restrict__ F0, const float* __restrict__ F1,
                 const float* __restrict__ F2,
                 float* __restrict__ out, HashMeta m, int npts)
{
  #pragma clang fp contract(off)
  const int lane = threadIdx.x & 63;
  const int n = blockIdx.x * (blockDim.x >> 6) + (threadIdx.x >> 6);
  if (n >= npts) return;

  const float4 xv = *reinterpret_cast<const float4*>(xin + (size_t)n*4);
  Coords C;
  compute_coords(xv.x, xv.y, xv.z, xv.w, wbv, C);

  const float* Fs[3] = {F0, F1, F2};
  float delta[3];
  #pragma unroll
  for (int i = 0; i < 3; ++i) {
    const float prod = plane_prod<TR>(Fs[i], C, lane);
    float acc = rlane(prod, 0);
    #pragma unroll
    for (int c2 = 1; c2 < 64; ++c2) acc += rlane(prod, c2);
    delta[i] = acc;
  }

  const float emax = (float)(1.0 - 1e-6);
  float enc[3];
  #pragma unroll
  for (int i = 0; i < 3; ++i)
    enc[i] = fminf(fmaxf(C.inp[i] + delta[i], 0.0f), emax);

  const int l = lane >> 2;
  const int q = lane & 3;
  const float sc = m.scalef[l];
  float i0f[3], i1f[3], off[3];
  #pragma unroll
  for (int d = 0; d < 3; ++d) {
    const float fx = enc[d] * sc;
    i0f[d] = floorf(fx);
    off[d] = fx - i0f[d];
    i1f[d] = floorf(fx + 1.0f);
  }
  const long long base = m.offs[l];
  const long long s1   = m.s1[l];
  const bool use_hash  = (l >= m.start_hash);
  const int by = q >> 1, bz = q & 1;
  const long long jy = (long long)(by ? i1f[1] : i0f[1]);
  const long long jz = (long long)(bz ? i1f[2] : i0f[2]);
  long long ypart, zpart;
  if (use_hash) { ypart = jy * 19349663LL; zpart = jz * 83492791LL; }
  else          { ypart = jy * s1;         zpart = jz; }
  float a0 = 0.0f, a1 = 0.0f;
  #pragma unroll
  for (int ci = 0; ci < 2; ++ci) {
    const int bx = ci;
    const long long jx = (long long)(bx ? i1f[0] : i0f[0]);
    long long idx;
    if (use_hash) {
      idx = mod_ne(jx ^ ypart ^ zpart, m.nent, m.magic) + base;
    } else {
      idx = jx * (s1*s1) + ypart + zpart + base;
    }
    const float w = (bx ? off[0] : 1.0f - off[0])
                  * (by ? off[1] : 1.0f - off[1])
                  * (bz ? off[2] : 1.0f - off[2]);
    const float2 tvv = *reinterpret_cast<const float2*>(table + idx*2);
    a0 += w * tvv.x;
    a1 += w * tvv.y;
  }
  a0 += __shfl_xor(a0, 1); a0 += __shfl_xor(a0, 2);
  a1 += __shfl_xor(a1, 1); a1 += __shfl_xor(a1, 2);
  if (q == 0)
    *reinterpret_cast<float2*>(out + (size_t)n*32 + l*2) = make_float2(a0, a1);
}

// ---------------- host ----------------
static bool isprime_ll(long long n) {
  if (n < 2) return false;
  for (long long i = 2; i*i <= n; ++i) if (n % i == 0) return false;
  return true;
}

extern "C" void kernel_launch(void* const* d_in, const int* in_sizes, int n_in,
                              void* d_out, int out_size, void* d_ws, size_t ws_size,
                              hipStream_t stream)
{
  const float* x     = (const float*)d_in[0];
  const float* wbv   = (const float*)d_in[1];
  const float* table = (const float*)d_in[2];
  const float* f0    = (const float*)d_in[3];
  const float* f1    = (const float*)d_in[4];
  const float* f2    = (const float*)d_in[5];
  float* out = (float*)d_out;
  const int npts = in_sizes[0] / 4;

  HashMeta m;
  long long ne = 1LL << 19;
  while (!isprime_ll(ne)) ne++;
  m.nent  = ne;
  m.magic = (~0ULL) / (unsigned long long)ne;  // q err <=1, corrected by cond-sub
  // SCALES: replicate Python int(16 * (128**(1/15))**i) via long-double chain
  const long double bl = powl(2.0L, 7.0L / 15.0L);   // 128^(1/15)
  const double      bd = (double)bl;
  long double p = 1.0L;
  long long off = 0; int sh = -1;
  for (int i = 0; i < 16; ++i) {
    const int res = (int)(16.0 * (double)p);
    m.scalef[i] = (float)res;
    m.s1[i]     = res + 1;
    m.offs[i]   = off;
    long long cnt = (long long)(res+1)*(res+1)*(res+1);
    if (cnt > ne) { if (sh < 0) sh = i; cnt = ne; }
    off += cnt;
    p *= (long double)bd;
  }
  m.start_hash = (sh < 0) ? 16 : sh;

  const size_t needT = (size_t)3 * TFEAT_ELEMS * sizeof(float);
  const size_t needP = (size_t)3 * 64 * npts * sizeof(float);
  const size_t needE = (size_t)npts * 4 * sizeof(float);
  const size_t needH = (size_t)npts * 16 * sizeof(float2);
  const int blocks1 = (npts + 3) / 4;     // K1: 4 points per 256-thr block
  const int blocksN = (npts + 255) / 256; // 1 thread per point
  const int blocksX = (npts + 255) / 256; // hash: blocks per level
  const size_t needI = (size_t)npts * sizeof(int)
                     + (size_t)2 * blocksN * 100 * sizeof(int)
                     + 256 * sizeof(int);

  if (ws_size >= needT + needP + needE + needH + needI) {
    float*   T  = (float*)d_ws;
    float*   P  = T + (size_t)3 * TFEAT_ELEMS;
    float4*  E  = (float4*)(P + (size_t)3 * 64 * npts);
    float2*  H  = (float2*)(E + npts);
    int*     I  = (int*)(H + (size_t)16 * npts);  // idx[npts]
    int*     Hb = I + npts;                       // per-block hist
    int*     Ob = Hb + (size_t)blocksN * 100;     // per-block partial offsets
    int*     Tt = Ob + (size_t)blocksN * 100;     // tot[100]
    dim3 tg(600, 3);
    // atomic-free t-bucket sort (output order-independent -> deterministic)
    sort_hist_k<<<blocksN, 256, 0, stream>>>(x, Hb, npts);
    sort_scan1_k<<<100, 256, 0, stream>>>(Hb, Ob, Tt, blocksN);
    sort_scatter_k<<<blocksN, 256, 0, stream>>>(x, Ob, Tt, I, npts);
    transpose_feats_k<<<tg, 256, 0, stream>>>(f0, f1, f2, T);
    delta_sorted_k<<<blocks1, 256, 0, stream>>>(x, wbv,
        T, T + TFEAT_ELEMS, T + (size_t)2*TFEAT_ELEMS, I, P, npts);
    fold_enc_k<<<blocksN, 256, 0, stream>>>(x, wbv, P, E, npts);
    hash_swz_k<<<blocksX * 16, 256, 0, stream>>>(E, table, H, m, npts, blocksX);
    untr_k<<<blocksN, 256, 0, stream>>>(H, out, npts);
  } else if (ws_size >= needT + needP + needE + needH) {
    float*   T = (float*)d_ws;
    float*   P = T + (size_t)3 * TFEAT_ELEMS;
    float4*  E = (float4*)(P + (size_t)3 * 64 * npts);
    float2*  H = (float2*)(E + npts);
    dim3 tg(600, 3);
    transpose_feats_k<<<tg, 256, 0, stream>>>(f0, f1, f2, T);
    delta_prods_k<<<blocks1, 256, 0, stream>>>(x, wbv,
        T, T + TFEAT_ELEMS, T + (size_t)2*TFEAT_ELEMS, P, npts);
    fold_enc_k<<<blocksN, 256, 0, stream>>>(x, wbv, P, E, npts);
    hash_swz_k<<<blocksX * 16, 256, 0, stream>>>(E, table, H, m, npts, blocksX);
    untr_k<<<blocksN, 256, 0, stream>>>(H, out, npts);
  } else if (ws_size >= needT + needP + needE) {
    float*   T = (float*)d_ws;
    float*   P = T + (size_t)3 * TFEAT_ELEMS;
    float4*  E = (float4*)(P + (size_t)3 * 64 * npts);
    dim3 tg(600, 3);
    transpose_feats_k<<<tg, 256, 0, stream>>>(f0, f1, f2, T);
    delta_prods_k<<<blocks1, 256, 0, stream>>>(x, wbv,
        T, T + TFEAT_ELEMS, T + (size_t)2*TFEAT_ELEMS, P, npts);
    fold_enc_k<<<blocksN, 256, 0, stream>>>(x, wbv, P, E, npts);
    dim3 hg(blocksX, 16);
    hash_lvl_k<<<hg, 256, 0, stream>>>(E, table, out, m, npts);
  } else if (ws_size >= needT) {
    float* T = (float*)d_ws;
    dim3 tg(600, 3);
    transpose_feats_k<<<tg, 256, 0, stream>>>(f0, f1, f2, T);
    dnerf_fused<true><<<blocks1, 256, 0, stream>>>(x, wbv, table,
        T, T + TFEAT_ELEMS, T + (size_t)2*TFEAT_ELEMS, out, m, npts);
  } else {
    dnerf_fused<false><<<blocks1, 256, 0, stream>>>(x, wbv, table,
        f0, f1, f2, out, m, npts);
  }
}

// Round 16
// 220.061 us; speedup vs baseline: 1.0450x; 1.0450x over previous
//
#include <hip/hip_runtime.h>
#include <math.h>
#include <stdint.h>
#include <stddef.h>

// CRITICAL: the reference check is vs a dtype-faithful f32 pipeline.
// FMA contraction in the delta/enc path perturbs floor(enc*scale) cells
// (each flip = ~1e-4 error >> 2e-6 threshold). Force separate rounding.
#pragma clang fp contract(off)

// feats: (3, 64, 100, 256) f32; table: (TOTAL_ENTRIES, 2) f32
// transposed feat layout in ws: [i][ (j*100+t)*256 + x ][c], c contiguous
#define TFEAT_ELEMS 4915200  // 3*100*256*64 per feat tensor

struct HashMeta {
  float     scalef[16];
  long long offs[16];
  long long s1[16];
  long long nent;
  unsigned long long magic;
  int start_hash;
};

__device__ __forceinline__ long long mod_ne(long long v, long long nent,
                                            unsigned long long magic) {
  unsigned long long uv = (unsigned long long)v;
  unsigned long long q  = __umul64hi(uv, magic);
  unsigned long long r  = uv - q * (unsigned long long)nent;
  if (r >= (unsigned long long)nent) r -= (unsigned long long)nent;
  return (long long)r;
}

__device__ __forceinline__ float rlane(float v, int l) {
  return __int_as_float(__builtin_amdgcn_readlane(__float_as_int(v), l));
}

// ---------------- feat transpose: [j][c][t][x] -> [(j*100+t)*256+x][c] ----
// (round-14 proven version)
__global__ __launch_bounds__(256)
void transpose_feats_k(const float* __restrict__ F0, const float* __restrict__ F1,
                       const float* __restrict__ F2, float* __restrict__ T)
{
  __shared__ float tile[64][65];   // tile[c][x]
  const int i  = blockIdx.y;
  const float* F = (i == 0) ? F0 : ((i == 1) ? F1 : F2);
  const int b  = blockIdx.x;      // 0..1199
  const int jt = b >> 2;          // j*100 + t, 0..299
  const int xt = (b & 3) << 6;    // x tile base
  const int j  = jt / 100;
  const int t  = jt - j * 100;
  const int tid = threadIdx.x;
  {
    const int cq = tid >> 4;          // 0..15
    const int x4 = (tid & 15) << 2;   // 0..60
    #pragma unroll
    for (int p = 0; p < 4; ++p) {
      const int c = p * 16 + cq;
      const float4 v = *reinterpret_cast<const float4*>(
          F + ((size_t)(j*64 + c)*100 + t)*256 + xt + x4);
      tile[c][x4+0] = v.x;
      tile[c][x4+1] = v.y;
      tile[c][x4+2] = v.z;
      tile[c][x4+3] = v.w;
    }
  }
  __syncthreads();
  {
    float* dst = T + (size_t)i * TFEAT_ELEMS + ((size_t)jt*256 + xt)*64;
    const int xq = tid >> 4;
    const int c4 = (tid & 15) << 2;
    #pragma unroll
    for (int p = 0; p < 4; ++p) {
      const int x = p * 16 + xq;
      float4 v;
      v.x = tile[c4+0][x];
      v.y = tile[c4+1][x];
      v.z = tile[c4+2][x];
      v.w = tile[c4+3][x];
      *reinterpret_cast<float4*>(dst + (size_t)x*64 + c4) = v;
    }
  }
}

// ------- t-bucket sort, atomic-free (parallel scan; order-independent) ----
__device__ __forceinline__ int clamp_t(float tf) {
  int t = (int)tf;
  return t < 0 ? 0 : (t > 99 ? 99 : t);
}

// pass 1: per-block LDS histogram -> Hb[b][100]
__global__ __launch_bounds__(256)
void sort_hist_k(const float* __restrict__ xin, int* __restrict__ Hb, int npts)
{
  __shared__ int h[100];
  if (threadIdx.x < 100) h[threadIdx.x] = 0;
  __syncthreads();
  const int n = blockIdx.x * 256 + threadIdx.x;
  if (n < npts) atomicAdd(&h[clamp_t(xin[(size_t)n*4 + 3])], 1);
  __syncthreads();
  if (threadIdx.x < 100) Hb[blockIdx.x * 100 + threadIdx.x] = h[threadIdx.x];
}

// pass 2a: per-bucket parallel exclusive prefix over blocks (chunked H-S)
// grid = 100 blocks (one per t), 256 threads
__global__ __launch_bounds__(256)
void sort_scan1_k(const int* __restrict__ Hb, int* __restrict__ Ob,
                  int* __restrict__ tot, int nb)
{
  __shared__ int s[256];
  const int t = blockIdx.x;
  int carry = 0;
  for (int base = 0; base < nb; base += 256) {
    const int b = base + (int)threadIdx.x;
    const int v = (b < nb) ? Hb[b*100 + t] : 0;
    s[threadIdx.x] = v;
    __syncthreads();
    #pragma unroll
    for (int o = 1; o < 256; o <<= 1) {
      const int add = (threadIdx.x >= (unsigned)o) ? s[threadIdx.x - o] : 0;
      __syncthreads();
      s[threadIdx.x] += add;
      __syncthreads();
    }
    const int incl = s[threadIdx.x];
    if (b < nb) Ob[b*100 + t] = carry + (incl - v);
    carry += s[255];
    __syncthreads();
  }
  if (threadIdx.x == 0) tot[t] = carry;
}

// pass 2b: exclusive scan of 100 bucket totals -> goff (LDS-staged)
__global__ __launch_bounds__(128)
void sort_scan2_k(const int* __restrict__ tot, int* __restrict__ goff)
{
  __shared__ int s[100];
  if (threadIdx.x < 100) s[threadIdx.x] = tot[threadIdx.x];
  __syncthreads();
  if (threadIdx.x == 0) {
    int acc = 0;
    for (int u = 0; u < 100; ++u) { const int v = s[u]; s[u] = acc; acc += v; }
  }
  __syncthreads();
  if (threadIdx.x < 100) goff[threadIdx.x] = s[threadIdx.x];
}

// pass 3: per-block LDS rank + scatter (no global atomics)
__global__ __launch_bounds__(256)
void sort_scatter_k(const float* __restrict__ xin, const int* __restrict__ Ob,
                    const int* __restrict__ goff, int* __restrict__ idx, int npts)
{
  __shared__ int cnt[100];
  if (threadIdx.x < 100) cnt[threadIdx.x] = 0;
  __syncthreads();
  const int n = blockIdx.x * 256 + threadIdx.x;
  if (n < npts) {
    const int t = clamp_t(xin[(size_t)n*4 + 3]);
    const int r = atomicAdd(&cnt[t], 1);   // LDS atomic: cheap
    idx[goff[t] + Ob[blockIdx.x * 100 + t] + r] = n;
  }
}

// ============ shared device helpers (exact reference op order) ============
struct Coords {
  float inp[3];
  int   yi0, yi1;
  float wy;
  bool  vy0, vy1;
  int   xi0[3], xi1[3];
  float wxv[3];
  bool  vx0[3], vx1[3];
};

__device__ __forceinline__ void compute_coords(const float px, const float py,
    const float pz, const float tfrm, const float* __restrict__ wbv, Coords& C)
{
  const float lo0 = wbv[0], lo1 = wbv[1], lo2 = wbv[2];
  const float hi0 = wbv[3], hi1 = wbv[4], hi2 = wbv[5];
  const float den = fmaxf(fmaxf(hi0-lo0, hi1-lo1), hi2-lo2);
  C.inp[0] = (fminf(fmaxf(px, lo0), hi0) - lo0) / den;
  C.inp[1] = (fminf(fmaxf(py, lo1), hi1) - lo1) / den;
  C.inp[2] = (fminf(fmaxf(pz, lo2), hi2) - lo2) / den;
  const float tn = tfrm / 99.0f;
  const float gy  = ((2.0f*tn - 1.0f) + 1.0f) * 0.5f * 99.0f;
  const float y0f = floorf(gy);
  C.wy  = gy - y0f;
  const float y1f = y0f + 1.0f;
  C.vy0 = (y0f >= 0.0f) && (y0f <= 99.0f);
  C.vy1 = (y1f >= 0.0f) && (y1f <= 99.0f);
  C.yi0 = (int)fminf(fmaxf(y0f, 0.0f), 99.0f);
  C.yi1 = (int)fminf(fmaxf(y1f, 0.0f), 99.0f);
  #pragma unroll
  for (int j = 0; j < 3; ++j) {
    const float gx  = ((2.0f*C.inp[j] - 1.0f) + 1.0f) * 0.5f * 255.0f;
    const float x0f = floorf(gx);
    C.wxv[j] = gx - x0f;
    const float x1f = x0f + 1.0f;
    C.vx0[j] = (x0f >= 0.0f) && (x0f <= 255.0f);
    C.vx1[j] = (x1f >= 0.0f) && (x1f <= 255.0f);
    C.xi0[j] = (int)fminf(fmaxf(x0f, 0.0f), 255.0f);
    C.xi1[j] = (int)fminf(fmaxf(x1f, 0.0f), 255.0f);
  }
}

// prod over 3 planes (fallback path) — exact reference ops
template<bool TR>
__device__ __forceinline__ float plane_prod(const float* __restrict__ Fi,
    const Coords& C, const int c)
{
  float prod = 1.0f;
  #pragma unroll
  for (int j = 0; j < 3; ++j) {
    float v00, v10, v01, v11;
    if (TR) {
      const float* bp = Fi + (size_t)j*100*256*64 + c;
      v00 = bp[((size_t)C.yi0*256 + C.xi0[j])*64];
      v10 = bp[((size_t)C.yi0*256 + C.xi1[j])*64];
      v01 = bp[((size_t)C.yi1*256 + C.xi0[j])*64];
      v11 = bp[((size_t)C.yi1*256 + C.xi1[j])*64];
    } else {
      const float* bp = Fi + ((size_t)(j*64 + c)*100)*256;
      v00 = bp[(size_t)C.yi0*256 + C.xi0[j]];
      v10 = bp[(size_t)C.yi0*256 + C.xi1[j]];
      v01 = bp[(size_t)C.yi1*256 + C.xi0[j]];
      v11 = bp[(size_t)C.yi1*256 + C.xi1[j]];
    }
    v00 = (C.vx0[j] && C.vy0) ? v00 : 0.0f;
    v10 = (C.vx1[j] && C.vy0) ? v10 : 0.0f;
    v01 = (C.vx0[j] && C.vy1) ? v01 : 0.0f;
    v11 = (C.vx1[j] && C.vy1) ? v11 : 0.0f;
    const float s = v00 * ((1.0f - C.wxv[j]) * (1.0f - C.wy))
                  + v10 * (C.wxv[j] * (1.0f - C.wy))
                  + v01 * ((1.0f - C.wxv[j]) * C.wy)
                  + v11 * (C.wxv[j] * C.wy);
    prod *= s;
  }
  return prod;
}

// ====== K1 core: plane products for point n -> P[n][i][c] (bit-exact) =====
__device__ __forceinline__ void delta_point(const float4 xv,
    const float* __restrict__ wbv, const float* __restrict__ F0,
    const float* __restrict__ F1, const float* __restrict__ F2,
    float* __restrict__ P, int n, int lane)
{
  Coords C;
  compute_coords(xv.x, xv.y, xv.z, xv.w, wbv, C);

  const float* Fs[3] = {F0, F1, F2};
  // y1-row weights are exactly +/-0 when wy==0, and forced 0 when !vy1 —
  // skipping those loads is bit-exact.
  const bool skipY1 = (C.wy == 0.0f) || !C.vy1;

  float v[3][3][4];
  #pragma unroll
  for (int i = 0; i < 3; ++i) {
    #pragma unroll
    for (int j = 0; j < 3; ++j) {
      const float* bp = Fs[i] + (size_t)j*100*256*64 + lane;
      v[i][j][0] = bp[((size_t)C.yi0*256 + C.xi0[j])*64];
      v[i][j][1] = bp[((size_t)C.yi0*256 + C.xi1[j])*64];
    }
  }
  if (!skipY1) {
    #pragma unroll
    for (int i = 0; i < 3; ++i) {
      #pragma unroll
      for (int j = 0; j < 3; ++j) {
        const float* bp = Fs[i] + (size_t)j*100*256*64 + lane;
        v[i][j][2] = bp[((size_t)C.yi1*256 + C.xi0[j])*64];
        v[i][j][3] = bp[((size_t)C.yi1*256 + C.xi1[j])*64];
      }
    }
  } else {
    #pragma unroll
    for (int i = 0; i < 3; ++i)
      #pragma unroll
      for (int j = 0; j < 3; ++j) { v[i][j][2] = 0.0f; v[i][j][3] = 0.0f; }
  }

  float* Pn = P + (size_t)n * 192;
  #pragma unroll
  for (int i = 0; i < 3; ++i) {
    float prod = 1.0f;
    #pragma unroll
    for (int j = 0; j < 3; ++j) {
      const float v00 = (C.vx0[j] && C.vy0) ? v[i][j][0] : 0.0f;
      const float v10 = (C.vx1[j] && C.vy0) ? v[i][j][1] : 0.0f;
      const float v01 = (C.vx0[j] && C.vy1) ? v[i][j][2] : 0.0f;
      const float v11 = (C.vx1[j] && C.vy1) ? v[i][j][3] : 0.0f;
      const float s = v00 * ((1.0f - C.wxv[j]) * (1.0f - C.wy))
                    + v10 * (C.wxv[j] * (1.0f - C.wy))
                    + v01 * ((1.0f - C.wxv[j]) * C.wy)
                    + v11 * (C.wxv[j] * C.wy);
      prod *= s;
    }
    Pn[i*64 + lane] = prod;
  }
}

// ===== K1 (sorted): t-bucketed points, XCD-contiguous t-ranges =====
__global__ __launch_bounds__(256)
void delta_sorted_k(const float* __restrict__ xin, const float* __restrict__ wbv,
                    const float* __restrict__ F0, const float* __restrict__ F1,
                    const float* __restrict__ F2, const int* __restrict__ idx,
                    float* __restrict__ P, int npts)
{
  #pragma clang fp contract(off)
  const int lane = threadIdx.x & 63;
  const int nb   = gridDim.x;
  const int bid  = blockIdx.x;
  // XCD = dispatch id % 8 (heuristic). Give XCD k the contiguous sorted
  // range so its L2 streams ~12 t-values' feat rows once.
  const int sb   = ((nb & 7) == 0) ? ((bid & 7)*(nb >> 3) + (bid >> 3)) : bid;
  const int pos  = sb * 4 + (threadIdx.x >> 6);
  if (pos >= npts) return;
  const int n = idx[pos];

  const float4 xv = *reinterpret_cast<const float4*>(xin + (size_t)n*4);
  delta_point(xv, wbv, F0, F1, F2, P, n, lane);
}

// ===== K1 (unsorted fallback, round-11 passing) =====
__global__ __launch_bounds__(256)
void delta_prods_k(const float* __restrict__ xin, const float* __restrict__ wbv,
                   const float* __restrict__ F0, const float* __restrict__ F1,
                   const float* __restrict__ F2,
                   float* __restrict__ P, int npts)
{
  #pragma clang fp contract(off)
  const int lane = threadIdx.x & 63;
  const int nb   = gridDim.x;
  const int bid  = blockIdx.x;
  const int sb   = ((nb & 7) == 0) ? ((bid & 7)*(nb >> 3) + (bid >> 3)) : bid;
  const int n    = sb * 4 + (threadIdx.x >> 6);
  if (n >= npts) return;

  const float4 xv = *reinterpret_cast<const float4*>(xin + (size_t)n*4);
  delta_point(xv, wbv, F0, F1, F2, P, n, lane);
}

// ===== K2a: fold (exact c=0..63 order) + enc -> E[n] (float4) =====
__global__ __launch_bounds__(256)
void fold_enc_k(const float* __restrict__ xin, const float* __restrict__ wbv,
                const float* __restrict__ P, float4* __restrict__ E, int npts)
{
  #pragma clang fp contract(off)
  const int n = blockIdx.x * 256 + threadIdx.x;
  if (n >= npts) return;

  const float4 xv = *reinterpret_cast<const float4*>(xin + (size_t)n*4);
  const float lo0 = wbv[0], lo1 = wbv[1], lo2 = wbv[2];
  const float hi0 = wbv[3], hi1 = wbv[4], hi2 = wbv[5];
  const float den = fmaxf(fmaxf(hi0-lo0, hi1-lo1), hi2-lo2);
  float inp[3];
  inp[0] = (fminf(fmaxf(xv.x, lo0), hi0) - lo0) / den;
  inp[1] = (fminf(fmaxf(xv.y, lo1), hi1) - lo1) / den;
  inp[2] = (fminf(fmaxf(xv.z, lo2), hi2) - lo2) / den;

  const float* Pn = P + (size_t)n * 192;
  float delta[3];
  #pragma unroll
  for (int i = 0; i < 3; ++i) {
    const float4* Pi = reinterpret_cast<const float4*>(Pn + i*64);
    float4 q[16];
    #pragma unroll
    for (int k = 0; k < 16; ++k) q[k] = Pi[k];
    float acc = q[0].x;
    acc += q[0].y; acc += q[0].z; acc += q[0].w;
    #pragma unroll
    for (int k = 1; k < 16; ++k) {
      acc += q[k].x; acc += q[k].y; acc += q[k].z; acc += q[k].w;
    }
    delta[i] = acc;
  }

  const float emax = (float)(1.0 - 1e-6);
  float4 e;
  e.x = fminf(fmaxf(inp[0] + delta[0], 0.0f), emax);
  e.y = fminf(fmaxf(inp[1] + delta[1], 0.0f), emax);
  e.z = fminf(fmaxf(inp[2] + delta[2], 0.0f), emax);
  e.w = 0.0f;
  E[n] = e;
}

// ===== K2b: hash encode, ONE XCD PER LEVEL, coalesced Hout writes =====
__global__ __launch_bounds__(256)
void hash_swz_k(const float4* __restrict__ E, const float* __restrict__ table,
                float2* __restrict__ Hout, HashMeta m, int npts, int bx)
{
  #pragma clang fp contract(off)
  const int id   = blockIdx.x;
  const int xcd  = id & 7;
  const int slot = id >> 3;
  const int lh   = slot / bx;         // 0 or 1
  const int c    = slot - lh * bx;
  const int l    = xcd + 8 * lh;      // wave-uniform level
  const int n    = c * 256 + threadIdx.x;
  if (n >= npts) return;

  const float4 e = E[n];
  const float enc[3] = {e.x, e.y, e.z};

  const float sc = m.scalef[l];
  float i0f[3], i1f[3], off[3];
  long long j0[3], j1[3];
  #pragma unroll
  for (int d = 0; d < 3; ++d) {
    const float fx = enc[d] * sc;
    i0f[d] = floorf(fx);
    off[d] = fx - i0f[d];
    i1f[d] = floorf(fx + 1.0f);   // matches ref: floor(fx + corner)
    j0[d] = (long long)i0f[d];
    j1[d] = (long long)i1f[d];
  }
  const long long base = m.offs[l];
  const long long s1   = m.s1[l];
  const bool use_hash  = (l >= m.start_hash);
  long long ym0, ym1, zm0, zm1, xm0, xm1;
  if (use_hash) {
    ym0 = j0[1] * 19349663LL;  ym1 = j1[1] * 19349663LL;
    zm0 = j0[2] * 83492791LL;  zm1 = j1[2] * 83492791LL;
    xm0 = j0[0];               xm1 = j1[0];
  } else {
    const long long s1s = s1 * s1;
    xm0 = j0[0] * s1s;  xm1 = j1[0] * s1s;
    ym0 = j0[1] * s1;   ym1 = j1[1] * s1;
    zm0 = j0[2];        zm1 = j1[2];
  }
  float2 tv[8];
  float  wv[8];
  #pragma unroll
  for (int cc = 0; cc < 8; ++cc) {
    const int bxc = cc >> 2, byc = (cc >> 1) & 1, bzc = cc & 1;
    const long long xm = bxc ? xm1 : xm0;
    const long long ym = byc ? ym1 : ym0;
    const long long zm = bzc ? zm1 : zm0;
    long long idx;
    if (use_hash) {
      idx = mod_ne(xm ^ ym ^ zm, m.nent, m.magic) + base;
    } else {
      idx = xm + ym + zm + base;
    }
    tv[cc] = *reinterpret_cast<const float2*>(table + idx*2);
    wv[cc] = (bxc ? off[0] : 1.0f - off[0])
           * (byc ? off[1] : 1.0f - off[1])
           * (bzc ? off[2] : 1.0f - off[2]);
  }
  float a0 = 0.0f, a1 = 0.0f;
  #pragma unroll
  for (int cc = 0; cc < 8; ++cc) {
    a0 += wv[cc] * tv[cc].x;
    a1 += wv[cc] * tv[cc].y;
  }
  Hout[(size_t)l * npts + n] = make_float2(a0, a1);
}

// ===== K2c: Hout[l][n] -> out[n][l*2..] (both sides coalesced) =====
__global__ __launch_bounds__(256)
void untr_k(const float2* __restrict__ Hout, float* __restrict__ out, int npts)
{
  const int n = blockIdx.x * 256 + threadIdx.x;
  if (n >= npts) return;
  float2 v[16];
  #pragma unroll
  for (int l = 0; l < 16; ++l) v[l] = Hout[(size_t)l * npts + n];
  #pragma unroll
  for (int l = 0; l < 16; ++l)
    *reinterpret_cast<float2*>(out + (size_t)n*32 + l*2) = v[l];
}

// ===== fallback K2b (round-10 passing): level-major 2D, direct out =====
__global__ __launch_bounds__(256)
void hash_lvl_k(const float4* __restrict__ E, const float* __restrict__ table,
                float* __restrict__ out, HashMeta m, int npts)
{
  #pragma clang fp contract(off)
  const int l = blockIdx.y;
  const int n = blockIdx.x * 256 + threadIdx.x;
  if (n >= npts) return;

  const float4 e = E[n];
  const float enc[3] = {e.x, e.y, e.z};

  const float sc = m.scalef[l];
  float i0f[3], i1f[3], off[3];
  long long j0[3], j1[3];
  #pragma unroll
  for (int d = 0; d < 3; ++d) {
    const float fx = enc[d] * sc;
    i0f[d] = floorf(fx);
    off[d] = fx - i0f[d];
    i1f[d] = floorf(fx + 1.0f);
    j0[d] = (long long)i0f[d];
    j1[d] = (long long)i1f[d];
  }
  const long long base = m.offs[l];
  const long long s1   = m.s1[l];
  const bool use_hash  = (l >= m.start_hash);
  long long ym0, ym1, zm0, zm1, xm0, xm1;
  if (use_hash) {
    ym0 = j0[1] * 19349663LL;  ym1 = j1[1] * 19349663LL;
    zm0 = j0[2] * 83492791LL;  zm1 = j1[2] * 83492791LL;
    xm0 = j0[0];               xm1 = j1[0];
  } else {
    const long long s1s = s1 * s1;
    xm0 = j0[0] * s1s;  xm1 = j1[0] * s1s;
    ym0 = j0[1] * s1;   ym1 = j1[1] * s1;
    zm0 = j0[2];        zm1 = j1[2];
  }
  float2 tv[8];
  float  wv[8];
  #pragma unroll
  for (int cc = 0; cc < 8; ++cc) {
    const int bx = cc >> 2, by = (cc >> 1) & 1, bz = cc & 1;
    const long long xm = bx ? xm1 : xm0;
    const long long ym = by ? ym1 : ym0;
    const long long zm = bz ? zm1 : zm0;
    long long idx;
    if (use_hash) {
      idx = mod_ne(xm ^ ym ^ zm, m.nent, m.magic) + base;
    } else {
      idx = xm + ym + zm + base;
    }
    tv[cc] = *reinterpret_cast<const float2*>(table + idx*2);
    wv[cc] = (bx ? off[0] : 1.0f - off[0])
           * (by ? off[1] : 1.0f - off[1])
           * (bz ? off[2] : 1.0f - off[2]);
  }
  float a0 = 0.0f, a1 = 0.0f;
  #pragma unroll
  for (int cc = 0; cc < 8; ++cc) {
    a0 += wv[cc] * tv[cc].x;
    a1 += wv[cc] * tv[cc].y;
  }
  *reinterpret_cast<float2*>(out + (size_t)n*32 + l*2) = make_float2(a0, a1);
}

// ========== fallback: monolithic (readlane fold) ==========================
template<bool TR>
__global__ __launch_bounds__(256)
void dnerf_fused(const float* __restrict__ xin, const float* __restrict__ wbv,
                 const float* __restrict__ table,
                 const float* __restrict__ F0, const float* __restrict__ F1,
                 const float* __restrict__ F2,
                 float* __restrict__ out, HashMeta m, int npts)
{
  #pragma clang fp contract(off)
  const int lane = threadIdx.x & 63;
  const int n = blockIdx.x * (blockDim.x >> 6) + (threadIdx.x >> 6);
  if (n >= npts) return;

  const float4 xv = *reinterpret_cast<const float4*>(xin + (size_t)n*4);
  Coords C;
  compute_coords(xv.x, xv.y, xv.z, xv.w, wbv, C);

  const float* Fs[3] = {F0, F1, F2};
  float delta[3];
  #pragma unroll
  for (int i = 0; i < 3; ++i) {
    const float prod = plane_prod<TR>(Fs[i], C, lane);
    float acc = rlane(prod, 0);
    #pragma unroll
    for (int c2 = 1; c2 < 64; ++c2) acc += rlane(prod, c2);
    delta[i] = acc;
  }

  const float emax = (float)(1.0 - 1e-6);
  float enc[3];
  #pragma unroll
  for (int i = 0; i < 3; ++i)
    enc[i] = fminf(fmaxf(C.inp[i] + delta[i], 0.0f), emax);

  const int l = lane >> 2;
  const int q = lane & 3;
  const float sc = m.scalef[l];
  float i0f[3], i1f[3], off[3];
  #pragma unroll
  for (int d = 0; d < 3; ++d) {
    const float fx = enc[d] * sc;
    i0f[d] = floorf(fx);
    off[d] = fx - i0f[d];
    i1f[d] = floorf(fx + 1.0f);
  }
  const long long base = m.offs[l];
  const long long s1   = m.s1[l];
  const bool use_hash  = (l >= m.start_hash);
  const int by = q >> 1, bz = q & 1;
  const long long jy = (long long)(by ? i1f[1] : i0f[1]);
  const long long jz = (long long)(bz ? i1f[2] : i0f[2]);
  long long ypart, zpart;
  if (use_hash) { ypart = jy * 19349663LL; zpart = jz * 83492791LL; }
  else          { ypart = jy * s1;         zpart = jz; }
  float a0 = 0.0f, a1 = 0.0f;
  #pragma unroll
  for (int ci = 0; ci < 2; ++ci) {
    const int bx = ci;
    const long long jx = (long long)(bx ? i1f[0] : i0f[0]);
    long long idx;
    if (use_hash) {
      idx = mod_ne(jx ^ ypart ^ zpart, m.nent, m.magic) + base;
    } else {
      idx = jx * (s1*s1) + ypart + zpart + base;
    }
    const float w = (bx ? off[0] : 1.0f - off[0])
                  * (by ? off[1] : 1.0f - off[1])
                  * (bz ? off[2] : 1.0f - off[2]);
    const float2 tvv = *reinterpret_cast<const float2*>(table + idx*2);
    a0 += w * tvv.x;
    a1 += w * tvv.y;
  }
  a0 += __shfl_xor(a0, 1); a0 += __shfl_xor(a0, 2);
  a1 += __shfl_xor(a1, 1); a1 += __shfl_xor(a1, 2);
  if (q == 0)
    *reinterpret_cast<float2*>(out + (size_t)n*32 + l*2) = make_float2(a0, a1);
}

// ---------------- host ----------------
static bool isprime_ll(long long n) {
  if (n < 2) return false;
  for (long long i = 2; i*i <= n; ++i) if (n % i == 0) return false;
  return true;
}

extern "C" void kernel_launch(void* const* d_in, const int* in_sizes, int n_in,
                              void* d_out, int out_size, void* d_ws, size_t ws_size,
                              hipStream_t stream)
{
  const float* x     = (const float*)d_in[0];
  const float* wbv   = (const float*)d_in[1];
  const float* table = (const float*)d_in[2];
  const float* f0    = (const float*)d_in[3];
  const float* f1    = (const float*)d_in[4];
  const float* f2    = (const float*)d_in[5];
  float* out = (float*)d_out;
  const int npts = in_sizes[0] / 4;

  HashMeta m;
  long long ne = 1LL << 19;
  while (!isprime_ll(ne)) ne++;
  m.nent  = ne;
  m.magic = (~0ULL) / (unsigned long long)ne;  // q err <=1, corrected by cond-sub
  // SCALES: replicate Python int(16 * (128**(1/15))**i) via long-double chain
  const long double bl = powl(2.0L, 7.0L / 15.0L);   // 128^(1/15)
  const double      bd = (double)bl;
  long double p = 1.0L;
  long long off = 0; int sh = -1;
  for (int i = 0; i < 16; ++i) {
    const int res = (int)(16.0 * (double)p);
    m.scalef[i] = (float)res;
    m.s1[i]     = res + 1;
    m.offs[i]   = off;
    long long cnt = (long long)(res+1)*(res+1)*(res+1);
    if (cnt > ne) { if (sh < 0) sh = i; cnt = ne; }
    off += cnt;
    p *= (long double)bd;
  }
  m.start_hash = (sh < 0) ? 16 : sh;

  const size_t needT = (size_t)3 * TFEAT_ELEMS * sizeof(float);
  const size_t needP = (size_t)3 * 64 * npts * sizeof(float);
  const size_t needE = (size_t)npts * 4 * sizeof(float);
  const size_t needH = (size_t)npts * 16 * sizeof(float2);
  const int blocks1 = (npts + 3) / 4;     // K1: 4 points per 256-thr block
  const int blocksN = (npts + 255) / 256; // 1 thread per point
  const int blocksX = (npts + 255) / 256; // hash: blocks per level
  const size_t needI = (size_t)npts * sizeof(int)
                     + (size_t)2 * blocksN * 100 * sizeof(int)
                     + 256 * sizeof(int);

  if (ws_size >= needT + needP + needE + needH + needI) {
    float*   T  = (float*)d_ws;
    float*   P  = T + (size_t)3 * TFEAT_ELEMS;
    float4*  E  = (float4*)(P + (size_t)3 * 64 * npts);
    float2*  H  = (float2*)(E + npts);
    int*     I  = (int*)(H + (size_t)16 * npts);  // idx[npts]
    int*     Hb = I + npts;                       // per-block hist
    int*     Ob = Hb + (size_t)blocksN * 100;     // per-block partial offsets
    int*     Tt = Ob + (size_t)blocksN * 100;     // tot[100]
    int*     Gf = Tt + 100;                       // goff[100]
    dim3 tg(1200, 3);
    // atomic-free t-bucket sort (output order-independent -> deterministic)
    sort_hist_k<<<blocksN, 256, 0, stream>>>(x, Hb, npts);
    sort_scan1_k<<<100, 256, 0, stream>>>(Hb, Ob, Tt, blocksN);
    sort_scan2_k<<<1, 128, 0, stream>>>(Tt, Gf);
    sort_scatter_k<<<blocksN, 256, 0, stream>>>(x, Ob, Gf, I, npts);
    transpose_feats_k<<<tg, 256, 0, stream>>>(f0, f1, f2, T);
    delta_sorted_k<<<blocks1, 256, 0, stream>>>(x, wbv,
        T, T + TFEAT_ELEMS, T + (size_t)2*TFEAT_ELEMS, I, P, npts);
    fold_enc_k<<<blocksN, 256, 0, stream>>>(x, wbv, P, E, npts);
    hash_swz_k<<<blocksX * 16, 256, 0, stream>>>(E, table, H, m, npts, blocksX);
    untr_k<<<blocksN, 256, 0, stream>>>(H, out, npts);
  } else if (ws_size >= needT + needP + needE + needH) {
    float*   T = (float*)d_ws;
    float*   P = T + (size_t)3 * TFEAT_ELEMS;
    float4*  E = (float4*)(P + (size_t)3 * 64 * npts);
    float2*  H = (float2*)(E + npts);
    dim3 tg(1200, 3);
    transpose_feats_k<<<tg, 256, 0, stream>>>(f0, f1, f2, T);
    delta_prods_k<<<blocks1, 256, 0, stream>>>(x, wbv,
        T, T + TFEAT_ELEMS, T + (size_t)2*TFEAT_ELEMS, P, npts);
    fold_enc_k<<<blocksN, 256, 0, stream>>>(x, wbv, P, E, npts);
    hash_swz_k<<<blocksX * 16, 256, 0, stream>>>(E, table, H, m, npts, blocksX);
    untr_k<<<blocksN, 256, 0, stream>>>(H, out, npts);
  } else if (ws_size >= needT + needP + needE) {
    float*   T = (float*)d_ws;
    float*   P = T + (size_t)3 * TFEAT_ELEMS;
    float4*  E = (float4*)(P + (size_t)3 * 64 * npts);
    dim3 tg(1200, 3);
    transpose_feats_k<<<tg, 256, 0, stream>>>(f0, f1, f2, T);
    delta_prods_k<<<blocks1, 256, 0, stream>>>(x, wbv,
        T, T + TFEAT_ELEMS, T + (size_t)2*TFEAT_ELEMS, P, npts);
    fold_enc_k<<<blocksN, 256, 0, stream>>>(x, wbv, P, E, npts);
    dim3 hg(blocksX, 16);
    hash_lvl_k<<<hg, 256, 0, stream>>>(E, table, out, m, npts);
  } else if (ws_size >= needT) {
    float* T = (float*)d_ws;
    dim3 tg(1200, 3);
    transpose_feats_k<<<tg, 256, 0, stream>>>(f0, f1, f2, T);
    dnerf_fused<true><<<blocks1, 256, 0, stream>>>(x, wbv, table,
        T, T + TFEAT_ELEMS, T + (size_t)2*TFEAT_ELEMS, out, m, npts);
  } else {
    dnerf_fused<false><<<blocks1, 256, 0, stream>>>(x, wbv, table,
        f0, f1, f2, out, m, npts);
  }
}